// Round 1
// baseline (1206.201 us; speedup 1.0000x reference)
//
#include <hip/hip_runtime.h>
#include <math.h>

typedef short s16x8 __attribute__((ext_vector_type(8)));
typedef short s16x4 __attribute__((ext_vector_type(4)));
typedef float f32x4 __attribute__((ext_vector_type(4)));

constexpr int NB = 32, CI = 64, IH = 128, IW = 128;
constexpr int PLANE = IH * IW;                 // 16384
constexpr int CHW = CI * PLANE;                // 1<<20
constexpr long long HALF = (long long)NB * CHW;
constexpr float EPS = 1e-5f;

// ws byte offsets
constexpr size_t WS_WCONV = 256;               // ushort[2][25][64][64]   (409,600 B)
constexpr size_t WS_WGATE = 409856;            // ushort[192][128]        (49,152 B)
constexpr size_t WS_XN = (size_t)1 << 20;      // x NHWC bf16 (64 MB)
constexpr size_t WS_HN = ((size_t)1 << 20) + ((size_t)64 << 20); // h NHWC bf16

__device__ __forceinline__ ushort f2bf(float f) {
    unsigned u = __float_as_uint(f);
    return (ushort)((u + 0x7fffu + ((u >> 16) & 1u)) >> 16);
}
__device__ __forceinline__ float bf2f(ushort h) { return __uint_as_float(((unsigned)h) << 16); }
__device__ __forceinline__ float sigf(float z) { return 1.0f / (1.0f + __expf(-z)); }
__device__ __forceinline__ float tanhfast(float z) { return 1.0f - 2.0f / (__expf(2.0f * z) + 1.0f); }
#define MFMA(a, b, c) __builtin_amdgcn_mfma_f32_16x16x32_bf16(a, b, c, 0, 0, 0)

// ---- pre-pass: weights -> bf16, MFMA-friendly layouts ----
// wconv[cv][tap][co][ci], wgate[n][k] (k = 0..63 x-ci, 64..127 h-ci)
__global__ __launch_bounds__(256) void k_prep_w(
    const float* __restrict__ w_xg, const float* __restrict__ w_hg,
    const float* __restrict__ w_exc, const float* __restrict__ w_inh,
    ushort* __restrict__ wconv, ushort* __restrict__ wgate)
{
    int idx = blockIdx.x * 256 + threadIdx.x;
    if (idx < 204800) {
        int cv = idx / 102400;
        int rem = idx - cv * 102400;
        int t = rem >> 12;
        int rem2 = rem & 4095;
        int co = rem2 >> 6, ci = rem2 & 63;
        const float* src = cv ? w_inh : w_exc;
        wconv[idx] = f2bf(src[(co * 64 + ci) * 25 + t]);
    } else if (idx < 204800 + 24576) {
        int g = idx - 204800;
        int n = g >> 7, k = g & 127;
        float v = (k < 64) ? w_xg[n * 64 + k] : w_hg[n * 64 + (k - 64)];
        wgate[g] = f2bf(v);
    }
}

// ---- pre-pass: x,h NCHW fp32 -> NHWC bf16 ----
__global__ __launch_bounds__(256) void k_nhwc(const float* __restrict__ x,
    const float* __restrict__ h, ushort* __restrict__ xn, ushort* __restrict__ hn)
{
    __shared__ float t[64][129];
    int bid = blockIdx.x;
    const float* src; ushort* dst;
    if (bid < 4096) { src = x; dst = xn; } else { src = h; dst = hn; bid -= 4096; }
    int b = bid >> 7, y = bid & 127;
    const float* s0 = src + (size_t)b * CHW + y * IW;
    for (int e = threadIdx.x; e < 8192; e += 256) {
        int ci = e >> 7, xx = e & 127;
        t[ci][xx] = s0[(size_t)ci * PLANE + xx];
    }
    __syncthreads();
    ushort* d0 = dst + ((size_t)(b * IH + y)) * IW * 64;
    for (int e = threadIdx.x; e < 8192; e += 256) {
        int xx = e >> 6, ci = e & 63;
        d0[e] = f2bf(t[ci][xx]);
    }
}

// ---- main fused cell: 2 rows/block, 512 threads, per-wave end-to-end pixel ownership ----
// Phases: [stage ch0 | S | conv ch0 | S | stage ch1 | S | conv ch1 | S |
//          ext-write + gates (reg-local) | S | epilogue]  -> 5 barriers / 2 rows.
__global__ __launch_bounds__(512, 4) void k_cell(
    const ushort* __restrict__ xn, const ushort* __restrict__ hn,
    const float* __restrict__ c,
    const ushort* __restrict__ wconv, const ushort* __restrict__ wgate,
    const float* __restrict__ b_xg, const float* __restrict__ b_hg,
    const float* __restrict__ b_exc, const float* __restrict__ b_inh,
    float* __restrict__ out, float* __restrict__ red)
{
    // union buffer: halo [6][132][32] ushort (25,344) | ext [2][64][260] ushort (33,280)
    __shared__ ushort sm[33280];
    __shared__ float reds[8], redq[8];
    const int tid = threadIdx.x;
    const int w = tid >> 6, lane = tid & 63;
    const int n16 = lane & 15, quad = lane >> 4;
    const int b = blockIdx.x >> 6, y0 = (blockIdx.x & 63) * 2;

    // ---- conv wave split: cv = exc/inh, pg = 64-px group (ro = row, ph = col-half) ----
    const int cv = w >> 2, pg = w & 3;
    const int ro = pg >> 1, ph = (pg & 1) * 64;

    f32x4 accC[4][4];
#pragma unroll
    for (int m = 0; m < 4; ++m)
#pragma unroll
        for (int n = 0; n < 4; ++n) accC[m][n] = (f32x4){0.f, 0.f, 0.f, 0.f};

#pragma unroll 1
    for (int ch = 0; ch < 2; ++ch) {
        const int ci0 = ch * 32;
        if (ch) __syncthreads();                       // ch0 halo reads done
        // stage 6 halo rows x 132 x 32ci as [dy][xi][ci] bf16 (OOB -> 0)
        for (int e = tid; e < 3168; e += 512) {
            int dy = e / 528;
            int rem = e - dy * 528;
            int xi = rem >> 2, cg = rem & 3;
            int yy = y0 + dy - 2, gx = xi - 2;
            s16x8 v = {0, 0, 0, 0, 0, 0, 0, 0};
            if ((unsigned)yy < 128u && (unsigned)gx < 128u)
                v = *(const s16x8*)(hn + (((size_t)(b * IH + yy)) * IW + gx) * 64 + ci0 + cg * 8);
            *(s16x8*)(sm + (dy * 132 + xi) * 32 + cg * 8) = v;
        }
        __syncthreads();
        const ushort* wcb = wconv + cv * 102400 + ci0 + quad * 8;
#pragma unroll
        for (int dy = 0; dy < 5; ++dy)
#pragma unroll
            for (int dx = 0; dx < 5; ++dx) {
                const int tap = dy * 5 + dx;
                s16x8 a[4];
#pragma unroll
                for (int mt = 0; mt < 4; ++mt)
                    a[mt] = *(const s16x8*)(sm + ((ro + dy) * 132 + ph + mt * 16 + n16 + dx) * 32 + quad * 8);
#pragma unroll
                for (int ct = 0; ct < 4; ++ct) {
                    s16x8 bb = *(const s16x8*)(wcb + tap * 4096 + (ct * 16 + n16) * 64);
#pragma unroll
                    for (int mt = 0; mt < 4; ++mt)
                        accC[mt][ct] = MFMA(a[mt], bb, accC[mt][ct]);
                }
            }
    }
    __syncthreads();                                   // halo dead -> ext writable

    // ---- write conv results (bias added) to ext[cv][co][px], px-dim padded to 260 ----
#pragma unroll
    for (int ct = 0; ct < 4; ++ct) {
        const int co = ct * 16 + n16;
        const float bias = (cv ? b_inh : b_exc)[co];
#pragma unroll
        for (int mt = 0; mt < 4; ++mt)
#pragma unroll
            for (int r = 0; r < 4; ++r) {
                int pxb = ro * 128 + ph + mt * 16 + quad * 4 + r;
                sm[(cv * 64 + co) * 260 + pxb] = f2bf(accC[mt][ct][r] + bias);
            }
    }

    // ---- gates GEMM (LDS-free; A direct from global). Wave w owns px w*32..+31 ----
    const int prow = w >> 2, pc0 = (w & 3) * 32;
    const ushort* xr = xn + ((size_t)(b * IH + y0 + prow) * IW + pc0) * 64;
    const ushort* hr = hn + ((size_t)(b * IH + y0 + prow) * IW + pc0) * 64;

    unsigned packIF[2][4][4];
    {   // pass 1: o-gate (n-tiles 8..11) -> store now, free regs
        f32x4 accO[2][4];
#pragma unroll
        for (int m = 0; m < 2; ++m)
#pragma unroll
            for (int g = 0; g < 4; ++g) accO[m][g] = (f32x4){0.f, 0.f, 0.f, 0.f};
#pragma unroll
        for (int kb = 0; kb < 4; ++kb) {
            const ushort* ab = (kb >= 2) ? hr : xr;
            const int ko = (kb & 1) * 32;
            s16x8 a0 = *(const s16x8*)(ab + n16 * 64 + ko + quad * 8);
            s16x8 a1 = *(const s16x8*)(ab + (16 + n16) * 64 + ko + quad * 8);
#pragma unroll
            for (int g = 0; g < 4; ++g) {
                s16x8 bb = *(const s16x8*)(wgate + ((g + 8) * 16 + n16) * 128 + kb * 32 + quad * 8);
                accO[0][g] = MFMA(a0, bb, accO[0][g]);
                accO[1][g] = MFMA(a1, bb, accO[1][g]);
            }
        }
#pragma unroll
        for (int ct = 0; ct < 4; ++ct) {
            const int co = ct * 16 + n16;
            const float bo = b_xg[128 + co] + b_hg[128 + co];
            float* obase = out + (size_t)b * CHW + (size_t)co * PLANE + (size_t)(y0 + prow) * IW + pc0;
#pragma unroll
            for (int mt = 0; mt < 2; ++mt)
#pragma unroll
                for (int r = 0; r < 4; ++r)
                    obase[mt * 16 + quad * 4 + r] = sigf(accO[mt][ct][r] + bo);
        }
    }
    {   // pass 2: i,f gates (n-tiles 0..7) -> packed bf16 pairs in regs
        f32x4 accIF[2][8];
#pragma unroll
        for (int m = 0; m < 2; ++m)
#pragma unroll
            for (int g = 0; g < 8; ++g) accIF[m][g] = (f32x4){0.f, 0.f, 0.f, 0.f};
#pragma unroll
        for (int kb = 0; kb < 4; ++kb) {
            const ushort* ab = (kb >= 2) ? hr : xr;
            const int ko = (kb & 1) * 32;
            s16x8 a0 = *(const s16x8*)(ab + n16 * 64 + ko + quad * 8);
            s16x8 a1 = *(const s16x8*)(ab + (16 + n16) * 64 + ko + quad * 8);
#pragma unroll
            for (int g = 0; g < 8; ++g) {
                s16x8 bb = *(const s16x8*)(wgate + (g * 16 + n16) * 128 + kb * 32 + quad * 8);
                accIF[0][g] = MFMA(a0, bb, accIF[0][g]);
                accIF[1][g] = MFMA(a1, bb, accIF[1][g]);
            }
        }
#pragma unroll
        for (int ct = 0; ct < 4; ++ct) {
            const int co = ct * 16 + n16;
            const float bi = b_xg[co] + b_hg[co];
            const float bff = b_xg[64 + co] + b_hg[64 + co];
#pragma unroll
            for (int mt = 0; mt < 2; ++mt)
#pragma unroll
                for (int r = 0; r < 4; ++r) {
                    float ig = sigf(accIF[mt][ct][r] + bi);
                    float fg = sigf(accIF[mt][ct + 4][r] + bff);
                    packIF[mt][ct][r] = (unsigned)f2bf(ig) | ((unsigned)f2bf(fg) << 16);
                }
        }
    }
    __syncthreads();                                   // ext visible

    // ---- epilogue in MFMA fragment layout: gates stay in registers ----
    float lsum = 0.f, lsq = 0.f;
    {
        const size_t rowoff = (size_t)b * CHW + (size_t)(y0 + prow) * IW + pc0;
        const float* cb = c + rowoff;
        float* ob = out + HALF + rowoff;
        const ushort* hcb = hn + ((size_t)(b * IH + y0 + prow) * IW + pc0) * 64;
        const int pq = w * 32 + quad * 4;              // + mt*16 (+ r via vector lane)
#pragma unroll
        for (int mt = 0; mt < 2; ++mt)
#pragma unroll
            for (int ct = 0; ct < 4; ++ct) {
                const int co = ct * 16 + n16;
                s16x4 e4 = *(const s16x4*)(sm + co * 260 + pq + mt * 16);
                s16x4 i4 = *(const s16x4*)(sm + (64 + co) * 260 + pq + mt * 16);
#pragma unroll
                for (int r = 0; r < 4; ++r) {
                    const int cl = mt * 16 + quad * 4 + r;       // 0..31 within wave's px
                    float ev = bf2f((ushort)e4[r]);
                    float iv = bf2f((ushort)i4[r]);
                    float hc = bf2f(hcb[(size_t)cl * 64 + co]);
                    unsigned pk = packIF[mt][ct][r];
                    float ig = bf2f((ushort)(pk & 0xffffu));
                    float fg = bf2f((ushort)(pk >> 16));
                    float hor = sigf(-iv) * (hc + ev);
                    float cold = cb[(size_t)co * PLANE + cl];
                    float cn = fg * cold + ig * hor;
                    ob[(size_t)co * PLANE + cl] = cn;
                    lsum += cn; lsq += cn * cn;
                }
            }
    }
#pragma unroll
    for (int off = 32; off > 0; off >>= 1) {
        lsum += __shfl_down(lsum, off, 64);
        lsq  += __shfl_down(lsq, off, 64);
    }
    if (lane == 0) { reds[w] = lsum; redq[w] = lsq; }
    __syncthreads();
    if (tid == 0) {
        float s = 0.f, q = 0.f;
#pragma unroll
        for (int i = 0; i < 8; ++i) { s += reds[i]; q += redq[i]; }
        atomicAdd(&red[2 * b], s);
        atomicAdd(&red[2 * b + 1], q);
    }
}

// ---- LayerNorm + tanh + o-gate multiply ----
__global__ __launch_bounds__(256) void k_norm(float* __restrict__ out, const float* __restrict__ red)
{
    const float invN = 1.0f / (float)CHW;
    size_t idx = ((size_t)blockIdx.x * 256 + threadIdx.x) * 4;
    int b = (int)(idx >> 20);
    float s = red[2 * b], q = red[2 * b + 1];
    float mean = s * invN;
    float var = q * invN - mean * mean;
    float r = rsqrtf(var + EPS);
    float4 o = *(const float4*)(out + idx);
    float4 cn = *(const float4*)(out + HALF + idx);
    float4 hnv;
    hnv.x = o.x * tanhfast((cn.x - mean) * r);
    hnv.y = o.y * tanhfast((cn.y - mean) * r);
    hnv.z = o.z * tanhfast((cn.z - mean) * r);
    hnv.w = o.w * tanhfast((cn.w - mean) * r);
    *(float4*)(out + idx) = hnv;
}

extern "C" void kernel_launch(void* const* d_in, const int* in_sizes, int n_in,
                              void* d_out, int out_size, void* d_ws, size_t ws_size,
                              hipStream_t stream) {
    const float* x     = (const float*)d_in[0];
    const float* h     = (const float*)d_in[1];
    const float* c     = (const float*)d_in[2];
    const float* w_xg  = (const float*)d_in[3];
    const float* b_xg  = (const float*)d_in[4];
    const float* w_hg  = (const float*)d_in[5];
    const float* b_hg  = (const float*)d_in[6];
    const float* w_exc = (const float*)d_in[7];
    const float* b_exc = (const float*)d_in[8];
    const float* w_inh = (const float*)d_in[9];
    const float* b_inh = (const float*)d_in[10];
    float* out = (float*)d_out;
    char* wsb = (char*)d_ws;
    float* red = (float*)wsb;
    ushort* wconv = (ushort*)(wsb + WS_WCONV);
    ushort* wgate = (ushort*)(wsb + WS_WGATE);
    ushort* xnh = (ushort*)(wsb + WS_XN);
    ushort* hnh = (ushort*)(wsb + WS_HN);

    hipMemsetAsync(red, 0, 256, stream);
    k_prep_w<<<896, 256, 0, stream>>>(w_xg, w_hg, w_exc, w_inh, wconv, wgate);
    k_nhwc<<<8192, 256, 0, stream>>>(x, h, xnh, hnh);
    k_cell<<<2048, 512, 0, stream>>>(xnh, hnh, c, wconv, wgate,
                                     b_xg, b_hg, b_exc, b_inh, out, red);
    k_norm<<<32768, 256, 0, stream>>>(out, red);
}

// Round 2
// 1186.635 us; speedup vs baseline: 1.0165x; 1.0165x over previous
//
#include <hip/hip_runtime.h>
#include <math.h>

typedef short s16x8 __attribute__((ext_vector_type(8)));
typedef short s16x4 __attribute__((ext_vector_type(4)));
typedef float f32x4 __attribute__((ext_vector_type(4)));

constexpr int NB = 32, CI = 64, IH = 128, IW = 128;
constexpr int PLANE = IH * IW;                 // 16384
constexpr int CHW = CI * PLANE;                // 1<<20
constexpr long long HALF = (long long)NB * CHW;
constexpr float EPS = 1e-5f;

// ws byte offsets
constexpr size_t WS_ZERO  = 256;               // 256 B of zeros (staging OOB redirect)
constexpr size_t WS_WCONV = 512;               // ushort[2][25][64][64]   (409,600 B)
constexpr size_t WS_WGATE = 512 + 409600;      // ushort[192][128]        (49,152 B)
constexpr size_t WS_XN = (size_t)1 << 20;      // x NHWC bf16 (64 MB)
constexpr size_t WS_HN = ((size_t)1 << 20) + ((size_t)64 << 20); // h NHWC bf16

constexpr int EXT_STRIDE = 268;                // ushorts; 536 B: 8B-aligned, odd word stride

__device__ __forceinline__ ushort f2bf(float f) {
    unsigned u = __float_as_uint(f);
    return (ushort)((u + 0x7fffu + ((u >> 16) & 1u)) >> 16);
}
__device__ __forceinline__ float bf2f(ushort h) { return __uint_as_float(((unsigned)h) << 16); }
__device__ __forceinline__ float sigf(float z) { return 1.0f / (1.0f + __expf(-z)); }
__device__ __forceinline__ float tanhfast(float z) { return 1.0f - 2.0f / (__expf(2.0f * z) + 1.0f); }
#define MFMA(a, b, c) __builtin_amdgcn_mfma_f32_16x16x32_bf16(a, b, c, 0, 0, 0)

// ---- pre-pass: weights -> bf16, MFMA-friendly layouts ----
// wconv[cv][tap][co][ci], wgate[n][k] (k = 0..63 x-ci, 64..127 h-ci)
// identity-tap trick: exc center tap gets +I so conv_exc(h) = h + exc directly.
__global__ __launch_bounds__(256) void k_prep_w(
    const float* __restrict__ w_xg, const float* __restrict__ w_hg,
    const float* __restrict__ w_exc, const float* __restrict__ w_inh,
    ushort* __restrict__ wconv, ushort* __restrict__ wgate)
{
    int idx = blockIdx.x * 256 + threadIdx.x;
    if (idx < 204800) {
        int cv = idx / 102400;
        int rem = idx - cv * 102400;
        int t = rem >> 12;
        int rem2 = rem & 4095;
        int co = rem2 >> 6, ci = rem2 & 63;
        const float* src = cv ? w_inh : w_exc;
        float v = src[(co * 64 + ci) * 25 + t];
        if (cv == 0 && t == 12 && co == ci) v += 1.0f;   // identity tap: h + exc
        wconv[idx] = f2bf(v);
    } else if (idx < 204800 + 24576) {
        int g = idx - 204800;
        int n = g >> 7, k = g & 127;
        float v = (k < 64) ? w_xg[n * 64 + k] : w_hg[n * 64 + (k - 64)];
        wgate[g] = f2bf(v);
    }
}

// ---- pre-pass: x,h NCHW fp32 -> NHWC bf16 ----
__global__ __launch_bounds__(256) void k_nhwc(const float* __restrict__ x,
    const float* __restrict__ h, ushort* __restrict__ xn, ushort* __restrict__ hn)
{
    __shared__ float t[64][129];
    int bid = blockIdx.x;
    const float* src; ushort* dst;
    if (bid < 4096) { src = x; dst = xn; } else { src = h; dst = hn; bid -= 4096; }
    int b = bid >> 7, y = bid & 127;
    const float* s0 = src + (size_t)b * CHW + y * IW;
    for (int e = threadIdx.x; e < 8192; e += 256) {
        int ci = e >> 7, xx = e & 127;
        t[ci][xx] = s0[(size_t)ci * PLANE + xx];
    }
    __syncthreads();
    ushort* d0 = dst + ((size_t)(b * IH + y)) * IW * 64;
    for (int e = threadIdx.x; e < 8192; e += 256) {
        int xx = e >> 6, ci = e & 63;
        d0[e] = f2bf(t[ci][xx]);
    }
}

// ---- main fused cell: 2 rows/block, 512 threads ----
// Phases: [stage ch0 | S | conv ch0 | S | stage ch1 | S | conv ch1 | S |
//          ext-write + gates (reg-local) | S | epilogue]  -> 5 barriers / 2 rows.
__global__ __launch_bounds__(512, 4) void k_cell(
    const ushort* __restrict__ xn, const ushort* __restrict__ hn,
    const float* __restrict__ c,
    const ushort* __restrict__ wconv, const ushort* __restrict__ wgate,
    const float* __restrict__ b_xg, const float* __restrict__ b_hg,
    const float* __restrict__ b_exc, const float* __restrict__ b_inh,
    const ushort* __restrict__ zpad,
    float* __restrict__ out, float* __restrict__ red)
{
    // union: halo [6][132][32] ushort (50,688 B) | ext [2][64][EXT_STRIDE] ushort (68,608 B)
    __shared__ ushort sm[2 * 64 * EXT_STRIDE];
    __shared__ float reds[8], redq[8];
    const int tid = threadIdx.x;
    const int w = tid >> 6, lane = tid & 63;
    const int n16 = lane & 15, quad = lane >> 4;
    const int b = blockIdx.x >> 6, y0 = (blockIdx.x & 63) * 2;

    // conv wave split: cv = exc/inh, pg = 64-px group (ro = row, ph = col-half)
    const int cv = w >> 2, pg = w & 3;
    const int ro = pg >> 1, ph = (pg & 1) * 64;

    f32x4 accC[4][4];
#pragma unroll
    for (int m = 0; m < 4; ++m)
#pragma unroll
        for (int n = 0; n < 4; ++n) accC[m][n] = (f32x4){0.f, 0.f, 0.f, 0.f};

#pragma unroll 1
    for (int ch = 0; ch < 2; ++ch) {
        const int ci0 = ch * 32;
        if (ch) __syncthreads();                       // ch0 halo reads done
        // stage 6 halo rows x 132 x 32ci as [dy][xi][ci] bf16, branch-free:
        // OOB lanes read a zero-pad buffer; direct global->LDS, 16B/lane.
        for (int k = 0; k < 7; ++k) {
            int e = k * 512 + tid;
            if (e < 3168) {
                int dy = e / 528;
                int rem = e - dy * 528;
                int xi = rem >> 2, cg = rem & 3;
                int yy = y0 + dy - 2, gx = xi - 2;
                bool ok = ((unsigned)yy < 128u) & ((unsigned)gx < 128u);
                const ushort* src = ok
                    ? (hn + (((size_t)(b * IH + yy)) * IW + gx) * 64 + ci0 + cg * 8)
                    : zpad;
                __builtin_amdgcn_global_load_lds(
                    (const __attribute__((address_space(1))) unsigned int*)src,
                    (__attribute__((address_space(3))) unsigned int*)(sm + (size_t)e * 8),
                    16, 0, 0);
            }
        }
        __syncthreads();
        const ushort* wcb = wconv + cv * 102400 + ci0 + quad * 8;
#pragma unroll
        for (int dy = 0; dy < 5; ++dy)
#pragma unroll
            for (int dx = 0; dx < 5; ++dx) {
                const int tap = dy * 5 + dx;
                s16x8 a[4];
#pragma unroll
                for (int mt = 0; mt < 4; ++mt)
                    a[mt] = *(const s16x8*)(sm + ((ro + dy) * 132 + ph + mt * 16 + n16 + dx) * 32 + quad * 8);
#pragma unroll
                for (int ct = 0; ct < 4; ++ct) {
                    s16x8 bb = *(const s16x8*)(wcb + tap * 4096 + (ct * 16 + n16) * 64);
#pragma unroll
                    for (int mt = 0; mt < 4; ++mt)
                        accC[mt][ct] = MFMA(a[mt], bb, accC[mt][ct]);
                }
            }
    }
    __syncthreads();                                   // halo dead -> ext writable

    // ---- write conv results (bias added) to ext[cv][co][px] as packed b64 ----
#pragma unroll
    for (int ct = 0; ct < 4; ++ct) {
        const int co = ct * 16 + n16;
        const float bias = (cv ? b_inh : b_exc)[co];
        ushort* eb = sm + (cv * 64 + co) * EXT_STRIDE;
#pragma unroll
        for (int mt = 0; mt < 4; ++mt) {
            int pxb = ro * 128 + ph + mt * 16 + quad * 4;
            unsigned lo = (unsigned)f2bf(accC[mt][ct][0] + bias)
                        | ((unsigned)f2bf(accC[mt][ct][1] + bias) << 16);
            unsigned hi = (unsigned)f2bf(accC[mt][ct][2] + bias)
                        | ((unsigned)f2bf(accC[mt][ct][3] + bias) << 16);
            uint2 pk; pk.x = lo; pk.y = hi;
            *(uint2*)(eb + pxb) = pk;
        }
    }

    // ---- gates GEMM (A direct from global). Wave w owns px w*32..+31 ----
    const int prow = w >> 2, pc0 = (w & 3) * 32;
    const ushort* xr = xn + ((size_t)(b * IH + y0 + prow) * IW + pc0) * 64;
    const ushort* hr = hn + ((size_t)(b * IH + y0 + prow) * IW + pc0) * 64;

    unsigned packIF[2][4][4];
    {   // pass 1: o-gate (n-tiles 8..11) -> float4 store now, free regs
        f32x4 accO[2][4];
#pragma unroll
        for (int m = 0; m < 2; ++m)
#pragma unroll
            for (int g = 0; g < 4; ++g) accO[m][g] = (f32x4){0.f, 0.f, 0.f, 0.f};
#pragma unroll
        for (int kb = 0; kb < 4; ++kb) {
            const ushort* ab = (kb >= 2) ? hr : xr;
            const int ko = (kb & 1) * 32;
            s16x8 a0 = *(const s16x8*)(ab + n16 * 64 + ko + quad * 8);
            s16x8 a1 = *(const s16x8*)(ab + (16 + n16) * 64 + ko + quad * 8);
#pragma unroll
            for (int g = 0; g < 4; ++g) {
                s16x8 bb = *(const s16x8*)(wgate + ((g + 8) * 16 + n16) * 128 + kb * 32 + quad * 8);
                accO[0][g] = MFMA(a0, bb, accO[0][g]);
                accO[1][g] = MFMA(a1, bb, accO[1][g]);
            }
        }
#pragma unroll
        for (int ct = 0; ct < 4; ++ct) {
            const int co = ct * 16 + n16;
            const float bo = b_xg[128 + co] + b_hg[128 + co];
            float* obase = out + (size_t)b * CHW + (size_t)co * PLANE + (size_t)(y0 + prow) * IW + pc0;
#pragma unroll
            for (int mt = 0; mt < 2; ++mt) {
                f32x4 og;
#pragma unroll
                for (int r = 0; r < 4; ++r) og[r] = sigf(accO[mt][ct][r] + bo);
                *(f32x4*)(obase + mt * 16 + quad * 4) = og;
            }
        }
    }
    {   // pass 2: i,f gates (n-tiles 0..7) -> packed bf16 pairs in regs
        f32x4 accIF[2][8];
#pragma unroll
        for (int m = 0; m < 2; ++m)
#pragma unroll
            for (int g = 0; g < 8; ++g) accIF[m][g] = (f32x4){0.f, 0.f, 0.f, 0.f};
#pragma unroll
        for (int kb = 0; kb < 4; ++kb) {
            const ushort* ab = (kb >= 2) ? hr : xr;
            const int ko = (kb & 1) * 32;
            s16x8 a0 = *(const s16x8*)(ab + n16 * 64 + ko + quad * 8);
            s16x8 a1 = *(const s16x8*)(ab + (16 + n16) * 64 + ko + quad * 8);
#pragma unroll
            for (int g = 0; g < 8; ++g) {
                s16x8 bb = *(const s16x8*)(wgate + (g * 16 + n16) * 128 + kb * 32 + quad * 8);
                accIF[0][g] = MFMA(a0, bb, accIF[0][g]);
                accIF[1][g] = MFMA(a1, bb, accIF[1][g]);
            }
        }
#pragma unroll
        for (int ct = 0; ct < 4; ++ct) {
            const int co = ct * 16 + n16;
            const float bi = b_xg[co] + b_hg[co];
            const float bff = b_xg[64 + co] + b_hg[64 + co];
#pragma unroll
            for (int mt = 0; mt < 2; ++mt)
#pragma unroll
                for (int r = 0; r < 4; ++r) {
                    float ig = sigf(accIF[mt][ct][r] + bi);
                    float fg = sigf(accIF[mt][ct + 4][r] + bff);
                    packIF[mt][ct][r] = (unsigned)f2bf(ig) | ((unsigned)f2bf(fg) << 16);
                }
        }
    }
    __syncthreads();                                   // ext visible

    // ---- epilogue in MFMA fragment layout, fully vectorized (float4) ----
    // identity-tap: ext[0] already holds (h + exc + b_exc); hor = sig(-inh)*ext0
    float lsum = 0.f, lsq = 0.f;
    {
        const size_t rowoff = (size_t)b * CHW + (size_t)(y0 + prow) * IW + pc0;
        const float* cb = c + rowoff;
        float* ob = out + HALF + rowoff;
        const int pxb0 = prow * 128 + pc0;
#pragma unroll
        for (int mt = 0; mt < 2; ++mt)
#pragma unroll
            for (int ct = 0; ct < 4; ++ct) {
                const int co = ct * 16 + n16;
                const int po = mt * 16 + quad * 4;
                s16x4 e4 = *(const s16x4*)(sm + co * EXT_STRIDE + pxb0 + po);
                s16x4 i4 = *(const s16x4*)(sm + (64 + co) * EXT_STRIDE + pxb0 + po);
                f32x4 cold = *(const f32x4*)(cb + (size_t)co * PLANE + po);
                f32x4 cn;
#pragma unroll
                for (int r = 0; r < 4; ++r) {
                    float ev = bf2f((ushort)e4[r]);
                    float iv = bf2f((ushort)i4[r]);
                    unsigned pk = packIF[mt][ct][r];
                    float ig = bf2f((ushort)(pk & 0xffffu));
                    float fg = bf2f((ushort)(pk >> 16));
                    float hor = sigf(-iv) * ev;
                    cn[r] = fg * cold[r] + ig * hor;
                    lsum += cn[r]; lsq += cn[r] * cn[r];
                }
                *(f32x4*)(ob + (size_t)co * PLANE + po) = cn;
            }
    }
#pragma unroll
    for (int off = 32; off > 0; off >>= 1) {
        lsum += __shfl_down(lsum, off, 64);
        lsq  += __shfl_down(lsq, off, 64);
    }
    if (lane == 0) { reds[w] = lsum; redq[w] = lsq; }
    __syncthreads();
    if (tid == 0) {
        float s = 0.f, q = 0.f;
#pragma unroll
        for (int i = 0; i < 8; ++i) { s += reds[i]; q += redq[i]; }
        atomicAdd(&red[2 * b], s);
        atomicAdd(&red[2 * b + 1], q);
    }
}

// ---- LayerNorm + tanh + o-gate multiply ----
__global__ __launch_bounds__(256) void k_norm(float* __restrict__ out, const float* __restrict__ red)
{
    const float invN = 1.0f / (float)CHW;
    size_t idx = ((size_t)blockIdx.x * 256 + threadIdx.x) * 4;
    int b = (int)(idx >> 20);
    float s = red[2 * b], q = red[2 * b + 1];
    float mean = s * invN;
    float var = q * invN - mean * mean;
    float r = rsqrtf(var + EPS);
    float4 o = *(const float4*)(out + idx);
    float4 cn = *(const float4*)(out + HALF + idx);
    float4 hnv;
    hnv.x = o.x * tanhfast((cn.x - mean) * r);
    hnv.y = o.y * tanhfast((cn.y - mean) * r);
    hnv.z = o.z * tanhfast((cn.z - mean) * r);
    hnv.w = o.w * tanhfast((cn.w - mean) * r);
    *(float4*)(out + idx) = hnv;
}

extern "C" void kernel_launch(void* const* d_in, const int* in_sizes, int n_in,
                              void* d_out, int out_size, void* d_ws, size_t ws_size,
                              hipStream_t stream) {
    const float* x     = (const float*)d_in[0];
    const float* h     = (const float*)d_in[1];
    const float* c     = (const float*)d_in[2];
    const float* w_xg  = (const float*)d_in[3];
    const float* b_xg  = (const float*)d_in[4];
    const float* w_hg  = (const float*)d_in[5];
    const float* b_hg  = (const float*)d_in[6];
    const float* w_exc = (const float*)d_in[7];
    const float* b_exc = (const float*)d_in[8];
    const float* w_inh = (const float*)d_in[9];
    const float* b_inh = (const float*)d_in[10];
    float* out = (float*)d_out;
    char* wsb = (char*)d_ws;
    float* red = (float*)wsb;
    const ushort* zpad = (const ushort*)(wsb + WS_ZERO);
    ushort* wconv = (ushort*)(wsb + WS_WCONV);
    ushort* wgate = (ushort*)(wsb + WS_WGATE);
    ushort* xnh = (ushort*)(wsb + WS_XN);
    ushort* hnh = (ushort*)(wsb + WS_HN);

    hipMemsetAsync(wsb, 0, 512, stream);   // red accumulators + zero-pad buffer
    k_prep_w<<<896, 256, 0, stream>>>(w_xg, w_hg, w_exc, w_inh, wconv, wgate);
    k_nhwc<<<8192, 256, 0, stream>>>(x, h, xnh, hnh);
    k_cell<<<2048, 512, 0, stream>>>(xnh, hnh, c, wconv, wgate,
                                     b_xg, b_hg, b_exc, b_inh, zpad, out, red);
    k_norm<<<32768, 256, 0, stream>>>(out, red);
}